// Round 1
// baseline (20266.391 us; speedup 1.0000x reference)
//
#include <hip/hip_runtime.h>
#include <math.h>

// Problem constants (fixed by the reference)
#define T_STEPS 512
#define BATCH   64
#define HID     512
#define NROW    2048          // 4*HID rows of concatenated W
#define HHIST   16777216ULL   // T*B*H floats (offset of i_hist in d_out)

// ---------------------------------------------------------------------------
// activation helpers (fp32, clamped to avoid exp overflow)
// ---------------------------------------------------------------------------
__device__ __forceinline__ float sigf(float z) {
  z = fminf(fmaxf(z, -30.f), 30.f);
  return 1.f / (1.f + __expf(-z));
}
__device__ __forceinline__ float tanhf_(float v) {
  v = fminf(fmaxf(v, -15.f), 15.f);
  const float e = __expf(2.f * v);
  return (e - 1.f) / (e + 1.f);
}

// ---------------------------------------------------------------------------
// Kernel A: Zx[t][r][b] = b[r] + sum_k Wx[r][k] * x[t][b][k]
// r = g*512 + n, gate order g: 0=f,1=i,2=o,3=c (matches W concat in reference)
// x-part of each W row is columns [512,1024).
// Tiling: 128 r x 64 b per wg, BK=32, 256 threads, each thread 4r x 8b.
// ---------------------------------------------------------------------------
__global__ __launch_bounds__(256) void xgemm_kernel(
    const float* __restrict__ x,
    const float* __restrict__ Wf, const float* __restrict__ Wi,
    const float* __restrict__ Wo, const float* __restrict__ Wc,
    const float* __restrict__ bf, const float* __restrict__ bi,
    const float* __restrict__ bo, const float* __restrict__ bc,
    float* __restrict__ Zx)
{
  const int rtile = blockIdx.x;   // 0..15
  const int t     = blockIdx.y;   // 0..511
  const int g  = rtile >> 2;
  const int n0 = (rtile & 3) * 128;
  const float* Wg = (g == 0) ? Wf : (g == 1) ? Wi : (g == 2) ? Wo : Wc;
  const float* bg = (g == 0) ? bf : (g == 1) ? bi : (g == 2) ? bo : bc;

  __shared__ float Wt[32][132];   // [k][r] transposed, padded (16.9 KB)
  __shared__ float Xt[32][68];    // [k][b] transposed, padded ( 8.7 KB)

  const int tid = threadIdx.x;
  const int tr  = tid & 31;       // 4 r-rows each
  const int tb  = tid >> 5;       // 8 b-cols each

  float acc[4][8];
#pragma unroll
  for (int i = 0; i < 4; ++i)
#pragma unroll
    for (int j = 0; j < 8; ++j) acc[i][j] = 0.f;

  float biasv[4];
#pragma unroll
  for (int i = 0; i < 4; ++i) biasv[i] = bg[n0 + tr * 4 + i];

  const float* xt = x + (size_t)t * (BATCH * 512);

  for (int kc = 0; kc < 512; kc += 32) {
    // stage W tile (128 r x 32 k) -> Wt[k][r]
#pragma unroll
    for (int p = 0; p < 4; ++p) {
      const int r  = p * 32 + (tid >> 3);
      const int kk = (tid & 7) * 4;
      float4 v = *(const float4*)&Wg[(size_t)(n0 + r) * 1024 + 512 + kc + kk];
      Wt[kk + 0][r] = v.x; Wt[kk + 1][r] = v.y;
      Wt[kk + 2][r] = v.z; Wt[kk + 3][r] = v.w;
    }
    // stage X tile (64 b x 32 k) -> Xt[k][b]
    {
      const int b  = tid >> 2;
      const int kk = (tid & 3) * 8;
      float4 v0 = *(const float4*)&xt[b * 512 + kc + kk];
      float4 v1 = *(const float4*)&xt[b * 512 + kc + kk + 4];
      Xt[kk + 0][b] = v0.x; Xt[kk + 1][b] = v0.y;
      Xt[kk + 2][b] = v0.z; Xt[kk + 3][b] = v0.w;
      Xt[kk + 4][b] = v1.x; Xt[kk + 5][b] = v1.y;
      Xt[kk + 6][b] = v1.z; Xt[kk + 7][b] = v1.w;
    }
    __syncthreads();
#pragma unroll
    for (int kk = 0; kk < 32; ++kk) {
      float4 wv = *(const float4*)&Wt[kk][tr * 4];
      float4 x0 = *(const float4*)&Xt[kk][tb * 8];
      float4 x1 = *(const float4*)&Xt[kk][tb * 8 + 4];
      const float wa[4] = {wv.x, wv.y, wv.z, wv.w};
      const float xa[8] = {x0.x, x0.y, x0.z, x0.w, x1.x, x1.y, x1.z, x1.w};
#pragma unroll
      for (int i = 0; i < 4; ++i)
#pragma unroll
        for (int j = 0; j < 8; ++j)
          acc[i][j] = fmaf(wa[i], xa[j], acc[i][j]);
    }
    __syncthreads();
  }

  const int rg = g * 512 + n0 + tr * 4;
#pragma unroll
  for (int ir = 0; ir < 4; ++ir) {
    const float bv = biasv[ir];
    float4 o0 = make_float4(acc[ir][0] + bv, acc[ir][1] + bv,
                            acc[ir][2] + bv, acc[ir][3] + bv);
    float4 o1 = make_float4(acc[ir][4] + bv, acc[ir][5] + bv,
                            acc[ir][6] + bv, acc[ir][7] + bv);
    float* dst = Zx + ((size_t)t * NROW + rg + ir) * 64 + tb * 8;
    *(float4*)dst       = o0;
    *(float4*)(dst + 4) = o1;
  }
}

// ---------------------------------------------------------------------------
// Kernel B helpers
// ---------------------------------------------------------------------------

// Stage a 64x512 fp32 slab (h or x_t) into LDS with XOR swizzle:
//   lds_byte(b, k4) = b*2048 + ((k4*16) ^ ((b&7)<<4))
// so the b128 dot-loop reads (64 lanes = 64 b rows, same k) spread over all
// 8 bank groups (8-cycle byte floor instead of a same-bank pileup).
__device__ __forceinline__ void stage128k(float* hx, const float* src, int tid) {
  const float4* s4 = (const float4*)src;
#pragma unroll 4
  for (int i = 0; i < 16; ++i) {
    const int idx = tid + (i << 9);       // 512 threads x 16 = 8192 float4
    float4 v = s4[idx];
    const int bb = idx >> 7;
    const int k4 = idx & 127;
    *(float4*)((char*)hx + (bb << 11) + ((k4 << 4) ^ ((bb & 7) << 4))) = v;
  }
}

// Per-thread dot slice: thread (kq,b) accumulates 8 row-partials over its
// 64-element k-range. W reads are wave-uniform (broadcast); h reads swizzled.
__device__ __forceinline__ void dot_part(const float* Wl, const int wstride,
                                         const float* hx, int kq, int b,
                                         int koff, float acc[8]) {
#pragma unroll 2
  for (int k4 = 0; k4 < 16; ++k4) {
    const int kbyte = (kq << 8) + (k4 << 4);       // = ke*4 bytes
    const int ke    = (kq << 6) + (k4 << 2);       // element index
    float4 hv = *(const float4*)((const char*)hx + (b << 11) +
                                 (kbyte ^ ((b & 7) << 4)));
#pragma unroll
    for (int rr = 0; rr < 8; ++rr) {
      float4 wv = *(const float4*)&Wl[rr * wstride + koff + ke];
      acc[rr] = fmaf(hv.x, wv.x, acc[rr]);
      acc[rr] = fmaf(hv.y, wv.y, acc[rr]);
      acc[rr] = fmaf(hv.z, wv.z, acc[rr]);
      acc[rr] = fmaf(hv.w, wv.w, acc[rr]);
    }
  }
}

// Tree grid-barrier: 16 groups x 16 wgs. Agent-scope acq/rel atomics carry
// cross-XCD visibility of the h stores (per-XCD L2s are not coherent).
__device__ __forceinline__ void grid_barrier(unsigned* cnt, int w, int tid, int round) {
  __syncthreads();
  if (tid == 0) {
    unsigned* gc = cnt + 16 + ((w >> 4) << 5);     // 128B-spaced group counters
    unsigned prev = __hip_atomic_fetch_add(gc, 1u, __ATOMIC_ACQ_REL,
                                           __HIP_MEMORY_SCOPE_AGENT);
    if ((prev & 15u) == 15u)
      __hip_atomic_fetch_add(cnt, 1u, __ATOMIC_ACQ_REL,
                             __HIP_MEMORY_SCOPE_AGENT);
    const unsigned target = (unsigned)(round + 1) * 16u;
    while (__hip_atomic_load(cnt, __ATOMIC_ACQUIRE,
                             __HIP_MEMORY_SCOPE_AGENT) < target)
      __builtin_amdgcn_s_sleep(1);
  }
  __syncthreads();
}

// ---------------------------------------------------------------------------
// Kernel B: persistent cooperative recurrence. 256 wgs x 512 threads.
// wg w owns hidden units {2w, 2w+1}; its 8 Wh rows stay in LDS all 512 steps.
// INLINE_X fallback (small ws): full 1024-col W rows in LDS, x_t restaged and
// dotted in-kernel instead of reading precomputed Zx.
// ---------------------------------------------------------------------------
template<bool INLINE_X>
__global__ __launch_bounds__(512) void lstm_rec(
    const float* __restrict__ x,  const float* __restrict__ mask,
    const float* __restrict__ Wf, const float* __restrict__ Wi,
    const float* __restrict__ Wo, const float* __restrict__ Wc,
    const float* __restrict__ bf, const float* __restrict__ bi,
    const float* __restrict__ bo, const float* __restrict__ bc,
    const float* __restrict__ Zx,
    float* __restrict__ hbuf, unsigned* __restrict__ cnt,
    float* __restrict__ out)
{
  constexpr int WC = INLINE_X ? 1024 : 512;
  __shared__ float Wlds[8 * WC];      // 16 KB (fast) / 32 KB (inline)
  __shared__ float hx[64 * 512];      // 128 KB swizzled h (or x) slab
  float* zpart = hx + 64 * 512 - 4096;  // [8 kq][8 rr][64 b], aliased tail

  const int tid = threadIdx.x;
  const int w   = blockIdx.x;         // 0..255
  const int kq  = tid >> 6;           // k-slice 0..7
  const int b   = tid & 63;

  // Preload this wg's 8 W rows (rr = g*2+u -> row (2w+u) of gate-g matrix).
#pragma unroll
  for (int i = 0; i < WC / 256; ++i) {
    const int idx4 = tid + (i << 9);
    const int rr   = idx4 / (WC / 4);
    const int col  = (idx4 % (WC / 4)) * 4;
    const int g = rr >> 1, u = rr & 1;
    const float* Wrow =
        ((g == 0) ? Wf : (g == 1) ? Wi : (g == 2) ? Wo : Wc) +
        (size_t)(w * 2 + u) * 1024;
    *(float4*)&Wlds[rr * WC + col] = *(const float4*)&Wrow[col];
  }

  float biasv[4] = {0.f, 0.f, 0.f, 0.f};
  float c_r = 0.f, h_r = 0.f;
  if (INLINE_X && tid < 128) {
    const int u = tid >> 6;
    biasv[0] = bf[w * 2 + u]; biasv[1] = bi[w * 2 + u];
    biasv[2] = bo[w * 2 + u]; biasv[3] = bc[w * 2 + u];
  }
  __syncthreads();

  for (int t = 0; t < T_STEPS; ++t) {
    // stage h_prev (double-buffered in global, zeroed for t=0 by memset)
    stage128k(hx, hbuf + ((t & 1) << 15), tid);

    float zpre[4] = {0.f, 0.f, 0.f, 0.f};
    float mval = 0.f;
    if (tid < 128) {
      const int u = tid >> 6, bb = tid & 63;
      mval = mask[t * 64 + bb];
      if (INLINE_X) {
#pragma unroll
        for (int g = 0; g < 4; ++g) zpre[g] = biasv[g];
      } else {
#pragma unroll
        for (int g = 0; g < 4; ++g)
          zpre[g] = Zx[((size_t)t * NROW + g * 512 + (w * 2 + u)) * 64 + bb];
      }
    }
    __syncthreads();   // staging complete

    float acc[8];
#pragma unroll
    for (int rr = 0; rr < 8; ++rr) acc[rr] = 0.f;

    dot_part(Wlds, WC, hx, kq, b, 0, acc);

    if (INLINE_X) {
      __syncthreads();                                 // h reads done
      stage128k(hx, x + (size_t)t * (64 * 512), tid);  // restage x_t
      __syncthreads();
      dot_part(Wlds, WC, hx, kq, b, 512, acc);
    }

    __syncthreads();   // all hx reads done -> safe to write aliased zpart
#pragma unroll
    for (int rr = 0; rr < 8; ++rr)
      zpart[((kq << 3) + rr) * 64 + b] = acc[rr];
    __syncthreads();

    if (tid < 128) {
      const int u = tid >> 6, bb = tid & 63;
      float z[4];
#pragma unroll
      for (int g = 0; g < 4; ++g) {
        const int rr = g * 2 + u;
        float s = zpre[g];
#pragma unroll
        for (int q = 0; q < 8; ++q) s += zpart[((q << 3) + rr) * 64 + bb];
        z[g] = s;
      }
      const float f  = sigf(z[0]);
      const float ig = sigf(z[1]);
      const float o  = sigf(z[2]);
      const float ct = tanhf_(z[3]);
      float cn = f * c_r + ig * ct;
      cn = mval * cn + (1.f - mval) * c_r;
      c_r = cn;
      float hn = o * tanhf_(cn);
      hn = mval * hn + (1.f - mval) * h_r;
      h_r = hn;
      const int n = w * 2 + u;
      hbuf[(((t + 1) & 1) << 15) + bb * 512 + n] = hn;
      out[((size_t)t * 64 + bb) * 512 + n]          = hn;
      out[HHIST + ((size_t)t * 64 + bb) * 512 + n]  = ig;
      __threadfence();   // make h visible before the release below
    }

    if (t != T_STEPS - 1) grid_barrier(cnt, w, tid, t);
  }
}

// ---------------------------------------------------------------------------
// launch
// ---------------------------------------------------------------------------
extern "C" void kernel_launch(void* const* d_in, const int* in_sizes, int n_in,
                              void* d_out, int out_size, void* d_ws, size_t ws_size,
                              hipStream_t stream) {
  (void)in_sizes; (void)n_in; (void)out_size;
  // setup_inputs order: x, mask, Wf, bf, Wi, bi, Wc, bc, Wo, bo
  const float* x    = (const float*)d_in[0];
  const float* mask = (const float*)d_in[1];
  const float* Wf   = (const float*)d_in[2];
  const float* bf   = (const float*)d_in[3];
  const float* Wi   = (const float*)d_in[4];
  const float* bi   = (const float*)d_in[5];
  const float* Wc   = (const float*)d_in[6];
  const float* bc   = (const float*)d_in[7];
  const float* Wo   = (const float*)d_in[8];
  const float* bo   = (const float*)d_in[9];
  float* out = (float*)d_out;

  const size_t zx_bytes  = (size_t)T_STEPS * NROW * 64 * 4;   // 256 MiB
  const size_t h_bytes   = 2 * 64 * 512 * 4;                  // 256 KiB
  const size_t bar_bytes = 4096;
  const bool fast = ws_size >= zx_bytes + h_bytes + bar_bytes;

  float* Zx; float* hbuf;
  if (fast) {
    Zx   = (float*)d_ws;
    hbuf = (float*)((char*)d_ws + zx_bytes);
  } else {
    Zx   = nullptr;
    hbuf = (float*)d_ws;
  }
  unsigned* cnt = (unsigned*)((char*)hbuf + h_bytes);

  // zero h double-buffer + barrier counters (ws is poisoned, not re-poisoned)
  hipMemsetAsync(hbuf, 0, h_bytes + bar_bytes, stream);

  void* kargs[] = { (void*)&x, (void*)&mask, (void*)&Wf, (void*)&Wi,
                    (void*)&Wo, (void*)&Wc, (void*)&bf, (void*)&bi,
                    (void*)&bo, (void*)&bc, (void*)&Zx, (void*)&hbuf,
                    (void*)&cnt, (void*)&out };

  if (fast) {
    hipLaunchKernelGGL(xgemm_kernel, dim3(16, 512), dim3(256), 0, stream,
                       x, Wf, Wi, Wo, Wc, bf, bi, bo, bc, Zx);
    hipLaunchCooperativeKernel(reinterpret_cast<void*>(&lstm_rec<false>),
                               dim3(256), dim3(512), kargs, 0, stream);
  } else {
    hipLaunchCooperativeKernel(reinterpret_cast<void*>(&lstm_rec<true>),
                               dim3(256), dim3(512), kargs, 0, stream);
  }
}

// Round 2
// 9324.384 us; speedup vs baseline: 2.1735x; 2.1735x over previous
//
#include <hip/hip_runtime.h>
#include <math.h>

// Problem constants (fixed by the reference)
#define T_STEPS 512
#define BATCH   64
#define HID     512
#define NROW    2048          // 4*HID rows of concatenated W
#define HHIST   16777216ULL   // T*B*H floats (offset of i_hist in d_out)

// ---------------------------------------------------------------------------
// activation helpers (fp32, clamped to avoid exp overflow)
// ---------------------------------------------------------------------------
__device__ __forceinline__ float sigf(float z) {
  z = fminf(fmaxf(z, -30.f), 30.f);
  return 1.f / (1.f + __expf(-z));
}
__device__ __forceinline__ float tanhf_(float v) {
  v = fminf(fmaxf(v, -15.f), 15.f);
  const float e = __expf(2.f * v);
  return (e - 1.f) / (e + 1.f);
}

// ---------------------------------------------------------------------------
// Kernel A: Zx[t][r][b] = b[r] + sum_k Wx[r][k] * x[t][b][k]
// (unchanged from round 1 — ~0.8 ms, revisit once lstm_rec dominates less)
// ---------------------------------------------------------------------------
__global__ __launch_bounds__(256) void xgemm_kernel(
    const float* __restrict__ x,
    const float* __restrict__ Wf, const float* __restrict__ Wi,
    const float* __restrict__ Wo, const float* __restrict__ Wc,
    const float* __restrict__ bf, const float* __restrict__ bi,
    const float* __restrict__ bo, const float* __restrict__ bc,
    float* __restrict__ Zx)
{
  const int rtile = blockIdx.x;   // 0..15
  const int t     = blockIdx.y;   // 0..511
  const int g  = rtile >> 2;
  const int n0 = (rtile & 3) * 128;
  const float* Wg = (g == 0) ? Wf : (g == 1) ? Wi : (g == 2) ? Wo : Wc;
  const float* bg = (g == 0) ? bf : (g == 1) ? bi : (g == 2) ? bo : bc;

  __shared__ float Wt[32][132];   // [k][r] transposed, padded
  __shared__ float Xt[32][68];    // [k][b] transposed, padded

  const int tid = threadIdx.x;
  const int tr  = tid & 31;       // 4 r-rows each
  const int tb  = tid >> 5;       // 8 b-cols each

  float acc[4][8];
#pragma unroll
  for (int i = 0; i < 4; ++i)
#pragma unroll
    for (int j = 0; j < 8; ++j) acc[i][j] = 0.f;

  float biasv[4];
#pragma unroll
  for (int i = 0; i < 4; ++i) biasv[i] = bg[n0 + tr * 4 + i];

  const float* xt = x + (size_t)t * (BATCH * 512);

  for (int kc = 0; kc < 512; kc += 32) {
#pragma unroll
    for (int p = 0; p < 4; ++p) {
      const int r  = p * 32 + (tid >> 3);
      const int kk = (tid & 7) * 4;
      float4 v = *(const float4*)&Wg[(size_t)(n0 + r) * 1024 + 512 + kc + kk];
      Wt[kk + 0][r] = v.x; Wt[kk + 1][r] = v.y;
      Wt[kk + 2][r] = v.z; Wt[kk + 3][r] = v.w;
    }
    {
      const int b  = tid >> 2;
      const int kk = (tid & 3) * 8;
      float4 v0 = *(const float4*)&xt[b * 512 + kc + kk];
      float4 v1 = *(const float4*)&xt[b * 512 + kc + kk + 4];
      Xt[kk + 0][b] = v0.x; Xt[kk + 1][b] = v0.y;
      Xt[kk + 2][b] = v0.z; Xt[kk + 3][b] = v0.w;
      Xt[kk + 4][b] = v1.x; Xt[kk + 5][b] = v1.y;
      Xt[kk + 6][b] = v1.z; Xt[kk + 7][b] = v1.w;
    }
    __syncthreads();
#pragma unroll
    for (int kk = 0; kk < 32; ++kk) {
      float4 wv = *(const float4*)&Wt[kk][tr * 4];
      float4 x0 = *(const float4*)&Xt[kk][tb * 8];
      float4 x1 = *(const float4*)&Xt[kk][tb * 8 + 4];
      const float wa[4] = {wv.x, wv.y, wv.z, wv.w};
      const float xa[8] = {x0.x, x0.y, x0.z, x0.w, x1.x, x1.y, x1.z, x1.w};
#pragma unroll
      for (int i = 0; i < 4; ++i)
#pragma unroll
        for (int j = 0; j < 8; ++j)
          acc[i][j] = fmaf(wa[i], xa[j], acc[i][j]);
    }
    __syncthreads();
  }

  const int rg = g * 512 + n0 + tr * 4;
#pragma unroll
  for (int ir = 0; ir < 4; ++ir) {
    const float bv = biasv[ir];
    float4 o0 = make_float4(acc[ir][0] + bv, acc[ir][1] + bv,
                            acc[ir][2] + bv, acc[ir][3] + bv);
    float4 o1 = make_float4(acc[ir][4] + bv, acc[ir][5] + bv,
                            acc[ir][6] + bv, acc[ir][7] + bv);
    float* dst = Zx + ((size_t)t * NROW + rg + ir) * 64 + tb * 8;
    *(float4*)dst       = o0;
    *(float4*)(dst + 4) = o1;
  }
}

// ---------------------------------------------------------------------------
// Grid barrier: 16 groups x 16 wgs. RELAXED polling (no per-poll L2
// invalidate!) + exactly one release fence on entry and one acquire fence
// on exit per wg per step. Agent-scope fences carry cross-XCD visibility.
// ---------------------------------------------------------------------------
__device__ __forceinline__ void grid_barrier(unsigned* cnt, int w, int tid, int round) {
  __syncthreads();   // all waves' stores issued & drained (barrier semantics)
  if (tid == 0) {
    __builtin_amdgcn_fence(__ATOMIC_RELEASE, "agent");   // one L2 writeback
    unsigned* gc = cnt + 16 + ((w >> 4) << 5);           // 128B-spaced group counters
    unsigned prev = __hip_atomic_fetch_add(gc, 1u, __ATOMIC_RELAXED,
                                           __HIP_MEMORY_SCOPE_AGENT);
    if ((prev & 15u) == 15u)
      __hip_atomic_fetch_add(cnt, 1u, __ATOMIC_RELAXED,
                             __HIP_MEMORY_SCOPE_AGENT);
    const unsigned target = (unsigned)(round + 1) * 16u;
    while (__hip_atomic_load(cnt, __ATOMIC_RELAXED,
                             __HIP_MEMORY_SCOPE_AGENT) < target)
      __builtin_amdgcn_s_sleep(2);
    __builtin_amdgcn_fence(__ATOMIC_ACQUIRE, "agent");   // one L1+L2 invalidate
  }
  __syncthreads();
}

// ---------------------------------------------------------------------------
// Kernel B: persistent cooperative recurrence. 256 wgs x 512 threads.
// wg w owns hidden units {n0, n0+1} with n0 = (w&7)*64 + (w>>3)*2 so that
// (assuming round-robin blockIdx->XCD dispatch) each XCD owns a CONTIGUOUS
// 64-unit range -> out/hT cache lines are single-XCD (kills write amp).
// W rows (8 x 512 fp32, h-part) stay in LDS all 512 steps. h is exchanged
// through a [n][b]-layout global buffer, read directly in the dot loop
// (coalesced 256B rows; L2/L3-resident) — no LDS staging.
// ---------------------------------------------------------------------------
template<bool INLINE_X>
__global__ __launch_bounds__(512) void lstm_rec(
    const float* __restrict__ x,  const float* __restrict__ mask,
    const float* __restrict__ Wf, const float* __restrict__ Wi,
    const float* __restrict__ Wo, const float* __restrict__ Wc,
    const float* __restrict__ bf, const float* __restrict__ bi,
    const float* __restrict__ bo, const float* __restrict__ bc,
    const float* __restrict__ Zx,
    float* __restrict__ hT, unsigned* __restrict__ cnt,
    float* __restrict__ out)
{
  constexpr int WC = INLINE_X ? 1024 : 512;
  __shared__ float Wlds[8 * WC];      // 16 KB (fast) / 32 KB (inline)
  __shared__ float zpart[8 * 8 * 64]; // [kq][rr][b] partials, 16 KB

  const int tid = threadIdx.x;
  const int w   = blockIdx.x;          // 0..255
  const int kq  = tid >> 6;            // k-slice 0..7
  const int b   = tid & 63;
  const int n0  = ((w & 7) << 6) + ((w >> 3) << 1);  // XCD-grouped ownership

  // Preload this wg's 8 W rows (rr = g*2+u -> row (n0+u) of gate-g matrix).
#pragma unroll
  for (int i = 0; i < WC / 256; ++i) {
    const int idx4 = tid + (i << 9);
    const int rr   = idx4 / (WC / 4);
    const int col  = (idx4 % (WC / 4)) * 4;
    const int g = rr >> 1, u = rr & 1;
    const float* Wrow =
        ((g == 0) ? Wf : (g == 1) ? Wi : (g == 2) ? Wo : Wc) +
        (size_t)(n0 + u) * 1024;
    *(float4*)&Wlds[rr * WC + col] = *(const float4*)&Wrow[col];
  }

  float biasv[4] = {0.f, 0.f, 0.f, 0.f};
  float c_r = 0.f, h_r = 0.f;
  if (INLINE_X && tid < 128) {
    const int u = tid >> 6;
    biasv[0] = bf[n0 + u]; biasv[1] = bi[n0 + u];
    biasv[2] = bo[n0 + u]; biasv[3] = bc[n0 + u];
  }
  __syncthreads();

  for (int t = 0; t < T_STEPS; ++t) {
    // issue x-part / mask loads early (consumed after the dot)
    float zpre[4] = {0.f, 0.f, 0.f, 0.f};
    float mval = 0.f;
    if (tid < 128) {
      const int u = tid >> 6, bb = tid & 63;
      mval = mask[t * 64 + bb];
      if (INLINE_X) {
#pragma unroll
        for (int g = 0; g < 4; ++g) zpre[g] = biasv[g];
      } else {
#pragma unroll
        for (int g = 0; g < 4; ++g)
          zpre[g] = Zx[((size_t)t * NROW + g * 512 + (n0 + u)) * 64 + bb];
      }
    }

    // ---- dot: acc[rr] = sum over this thread's 64-k slice of W[rr][k]*h[k][b]
    float acc[8];
#pragma unroll
    for (int rr = 0; rr < 8; ++rr) acc[rr] = 0.f;

    {
      const float* hcur = hT + ((t & 1) << 15);   // [k][b], 128 KB
      const int k0 = kq << 6;
#pragma unroll
      for (int k4 = 0; k4 < 16; ++k4) {
        const int k = k0 + (k4 << 2);
        const float h0 = hcur[(k + 0) * 64 + b];
        const float h1 = hcur[(k + 1) * 64 + b];
        const float h2 = hcur[(k + 2) * 64 + b];
        const float h3 = hcur[(k + 3) * 64 + b];
#pragma unroll
        for (int rr = 0; rr < 8; ++rr) {
          float4 wv = *(const float4*)&Wlds[rr * WC + k];
          acc[rr] = fmaf(h0, wv.x, acc[rr]);
          acc[rr] = fmaf(h1, wv.y, acc[rr]);
          acc[rr] = fmaf(h2, wv.z, acc[rr]);
          acc[rr] = fmaf(h3, wv.w, acc[rr]);
        }
      }
    }

    if (INLINE_X) {   // fallback: x-part dotted in-kernel (uncoalesced, rare)
      const float* xt = x + (size_t)t * (64 * 512) + b * 512;
      const int k0 = kq << 6;
#pragma unroll
      for (int k4 = 0; k4 < 16; ++k4) {
        const int k = k0 + (k4 << 2);
        float4 xv = *(const float4*)&xt[k];
#pragma unroll
        for (int rr = 0; rr < 8; ++rr) {
          float4 wv = *(const float4*)&Wlds[rr * WC + 512 + k];
          acc[rr] = fmaf(xv.x, wv.x, acc[rr]);
          acc[rr] = fmaf(xv.y, wv.y, acc[rr]);
          acc[rr] = fmaf(xv.z, wv.z, acc[rr]);
          acc[rr] = fmaf(xv.w, wv.w, acc[rr]);
        }
      }
    }

#pragma unroll
    for (int rr = 0; rr < 8; ++rr)
      zpart[((kq << 3) + rr) * 64 + b] = acc[rr];
    __syncthreads();   // zpart complete

    if (tid < 128) {
      const int u = tid >> 6, bb = tid & 63;
      float z[4];
#pragma unroll
      for (int g = 0; g < 4; ++g) {
        const int rr = g * 2 + u;
        float s = zpre[g];
#pragma unroll
        for (int q = 0; q < 8; ++q) s += zpart[((q << 3) + rr) * 64 + bb];
        z[g] = s;
      }
      const float f  = sigf(z[0]);
      const float ig = sigf(z[1]);
      const float o  = sigf(z[2]);
      const float ct = tanhf_(z[3]);
      float cn = f * c_r + ig * ct;
      cn = mval * cn + (1.f - mval) * c_r;
      c_r = cn;
      float hn = o * tanhf_(cn);
      hn = mval * hn + (1.f - mval) * h_r;
      h_r = hn;
      const int n = n0 + u;
      // [n][b] layout: 64 lanes (bb) -> one contiguous 256B row, single writer
      hT[(((t + 1) & 1) << 15) + n * 64 + bb] = hn;
      out[((size_t)t * 64 + bb) * 512 + n]         = hn;
      out[HHIST + ((size_t)t * 64 + bb) * 512 + n] = ig;
    }

    if (t != T_STEPS - 1) grid_barrier(cnt, w, tid, t);
  }
}

// ---------------------------------------------------------------------------
// launch
// ---------------------------------------------------------------------------
extern "C" void kernel_launch(void* const* d_in, const int* in_sizes, int n_in,
                              void* d_out, int out_size, void* d_ws, size_t ws_size,
                              hipStream_t stream) {
  (void)in_sizes; (void)n_in; (void)out_size;
  // setup_inputs order: x, mask, Wf, bf, Wi, bi, Wc, bc, Wo, bo
  const float* x    = (const float*)d_in[0];
  const float* mask = (const float*)d_in[1];
  const float* Wf   = (const float*)d_in[2];
  const float* bf   = (const float*)d_in[3];
  const float* Wi   = (const float*)d_in[4];
  const float* bi   = (const float*)d_in[5];
  const float* Wc   = (const float*)d_in[6];
  const float* bc   = (const float*)d_in[7];
  const float* Wo   = (const float*)d_in[8];
  const float* bo   = (const float*)d_in[9];
  float* out = (float*)d_out;

  const size_t zx_bytes  = (size_t)T_STEPS * NROW * 64 * 4;   // 256 MiB
  const size_t h_bytes   = 2 * 64 * 512 * 4;                  // 256 KiB
  const size_t bar_bytes = 4096;
  const bool fast = ws_size >= zx_bytes + h_bytes + bar_bytes;

  float* Zx; float* hT;
  if (fast) {
    Zx = (float*)d_ws;
    hT = (float*)((char*)d_ws + zx_bytes);
  } else {
    Zx = nullptr;
    hT = (float*)d_ws;
  }
  unsigned* cnt = (unsigned*)((char*)hT + h_bytes);

  // zero h double-buffer + barrier counters (ws is poisoned, not re-poisoned)
  hipMemsetAsync(hT, 0, h_bytes + bar_bytes, stream);

  void* kargs[] = { (void*)&x, (void*)&mask, (void*)&Wf, (void*)&Wi,
                    (void*)&Wo, (void*)&Wc, (void*)&bf, (void*)&bi,
                    (void*)&bo, (void*)&bc, (void*)&Zx, (void*)&hT,
                    (void*)&cnt, (void*)&out };

  if (fast) {
    hipLaunchKernelGGL(xgemm_kernel, dim3(16, 512), dim3(256), 0, stream,
                       x, Wf, Wi, Wo, Wc, bf, bi, bo, bc, Zx);
    hipLaunchCooperativeKernel(reinterpret_cast<void*>(&lstm_rec<false>),
                               dim3(256), dim3(512), kargs, 0, stream);
  } else {
    hipLaunchCooperativeKernel(reinterpret_cast<void*>(&lstm_rec<true>),
                               dim3(256), dim3(512), kargs, 0, stream);
  }
}